// Round 4
// baseline (1124.529 us; speedup 1.0000x reference)
//
#include <hip/hip_runtime.h>

#define H_ 128
#define T_ 1024
#define B_ 512
#define I_ 13
#define LOG2E 1.4426950408889634f

typedef _Float16 half8 __attribute__((ext_vector_type(8)));
typedef float float4_ __attribute__((ext_vector_type(4)));

static __device__ __forceinline__ float fast_rcp(float v) {
  return __builtin_amdgcn_rcpf(v);
}
static __device__ __forceinline__ float fast_exp2(float v) {
  return __builtin_amdgcn_exp2f(v);
}
static __device__ __forceinline__ float sigmoid_f(float v) {
  return fast_rcp(1.0f + fast_exp2(-LOG2E * v));
}
static __device__ __forceinline__ float tanh_f(float v) {
  return 2.0f * fast_rcp(1.0f + fast_exp2(-2.0f * LOG2E * v)) - 1.0f;
}

// R9: trim the step critical path (R8 tied R5 at ~2180 cy/step; MFMA floor
// is ~780 cy/SIMD, so ~1000 cy is serial latency).
//  (1) no cross-lane exchange: acc[2g+1][0] already lives in lanes 0-31,
//      so lanes 0-31 activate BOTH col-groups (2 c-states, 2 ds_write_b16)
//      -- removes 4 ds_bpermute (~120cy LDS round-trips) per step.
//  (2) kc-chain split: gates = acc(kc0-2) + acc2(kc3-4); dependent MFMA
//      chain depth 5 -> 3, hidden under the 8-chain interleave.
//  (3) FC issued FIRST (depends only on af): its 4-deep dependent chain
//      overlaps the gate ladder instead of extending wave 3's tail.
// Structure unchanged: 256 WGs x 4 waves, 2 rows/WG, 1 wave/SIMD,
// weights VGPR-resident, zero vector-memory ops in the loop.
__global__ __launch_bounds__(256, 1) void lstm_fused(
    const float* __restrict__ x, const float* __restrict__ Wih,
    const float* __restrict__ Whh, const float* __restrict__ bih,
    const float* __restrict__ bhh, const float* __restrict__ Wfc,
    const float* __restrict__ bfc, float* __restrict__ out)
{
  // 64 KB: x(t) for both rows (f16), slots 13..15 zero (pad to k-chunk)
  __shared__ __align__(16) _Float16 xlds[T_][2][16];
  // 64 KB: logits ring, slot t holds logits for output row t (cols 0..6)
  __shared__ __align__(16) float lgring[T_][2][8];
  // 1.3 KB: double-buffered h (cols 0..127 used; stride 168 halfs)
  __shared__ __align__(16) _Float16 abuf[2][2][168];

  const int tid  = threadIdx.x;
  const int wave = tid >> 6;      // 0..3
  const int lane = tid & 63;
  const int n16  = lane & 15;
  const int quad = lane >> 4;
  const int wgb  = blockIdx.x * 2;

  // ---- W fragments: wave w owns tiles {g*8 + 2w + p : g=0..3, p=0..1} ----
  // (all 4 gates for col-groups 2w and 2w+1 -> cell update is wave-local)
  // B layout (16x16x32): lane holds B[k = quad*8 + j][n = n16]
  half8 wfrag[8][5];
  float biasv[8];
  #pragma unroll
  for (int ti = 0; ti < 8; ++ti) {
    const int g    = ti >> 1;
    const int p    = ti & 1;
    const int tile = g * 8 + 2 * wave + p;
    const int col  = tile * 16 + n16;
    biasv[ti] = bih[col] + bhh[col];
    #pragma unroll
    for (int kc = 0; kc < 5; ++kc) {
      half8 f;
      #pragma unroll
      for (int j = 0; j < 8; ++j) {
        const int k = kc * 32 + quad * 8 + j;
        float v = 0.0f;
        if (k < 128)            v = Whh[col * H_ + k];
        else if (k < 128 + I_)  v = Wih[col * I_ + (k - 128)];
        f[j] = (_Float16)v;
      }
      wfrag[ti][kc] = f;
    }
  }
  // FC tile (consumed by wave 3; loaded uniformly), k < 128 -> 4 chunks
  half8 wfc[4];
  const float biasfc = (n16 < 7) ? bfc[n16] : 0.0f;
  #pragma unroll
  for (int kc = 0; kc < 4; ++kc) {
    half8 f;
    #pragma unroll
    for (int j = 0; j < 8; ++j) {
      const int k = kc * 32 + quad * 8 + j;
      f[j] = (_Float16)((n16 < 7) ? Wfc[n16 * H_ + k] : 0.0f);
    }
    wfc[kc] = f;
  }

  // ---- phase 0: preload all x for this WG into LDS (f16), zero pads ----
  for (int idx = tid; idx < T_ * 2 * 16; idx += 256) {
    const int t  = idx >> 5;
    const int rw = (idx >> 4) & 1;
    const int ii = idx & 15;
    float v = 0.0f;
    if (ii < I_) v = x[((size_t)t * B_ + wgb + rw) * I_ + ii];
    xlds[t][rw][ii] = (_Float16)v;
  }
  for (int idx = tid; idx < 2 * 2 * 168; idx += 256)
    ((_Float16*)abuf)[idx] = (_Float16)0.0f;
  __syncthreads();

  // cell states: lanes 0-31 hold TWO col-groups each.
  // lane(0-15): batch row 0; lane(16-31): batch row 1 (D rows 0 and 4).
  // c0/h0 -> col 32w + n16 ; c1/h1 -> col 32w + 16 + n16.
  float c0 = 0.0f, c1 = 0.0f;
  const int  hrow = (lane >> 4) & 1;
  const bool aload = (n16 == 0) || (n16 == 4);  // A rows 0 and 4
  const int  arow  = n16 >> 2;

  half8 af[4];
  half8 af4;
  {
    half8 z;
    #pragma unroll
    for (int j = 0; j < 8; ++j) z[j] = (_Float16)0.0f;
    #pragma unroll
    for (int kc = 0; kc < 4; ++kc) af[kc] = z;
    af4 = z;
  }
  // preload x fragment for t=0 (xlds is static; prefetched ahead in-loop)
  if (aload && quad < 2)
    af4 = *(const half8*)&xlds[0][arow][quad * 8];

  float4_ acc[8], acc2[8];
  #pragma unroll
  for (int ti = 0; ti < 8; ++ti)
    #pragma unroll
    for (int r = 0; r < 4; ++r) { acc[ti][r] = 0.0f; acc2[ti][r] = 0.0f; }
  float4_ accf;
  #pragma unroll
  for (int r = 0; r < 4; ++r) accf[r] = 0.0f;

  // ---- phase 1: the recurrence. No vector-memory ops in this loop. ----
  for (int t = 0; t <= T_; ++t) {
    // A fragments: h chunks 0..3 from abuf (x chunk af4 prefetched)
    if (aload) {
      #pragma unroll
      for (int kc = 0; kc < 4; ++kc)
        af[kc] = *(const half8*)&abuf[t & 1][arow][kc * 32 + quad * 8];
    }

    // FC logits FIRST: depends only on af (h_t from the barrier-protected
    // buffer); its dependent chain overlaps the gate ladder below.
    if (wave == 3 && t >= 1) {
      accf[0] = biasfc;
      #pragma unroll
      for (int kc = 0; kc < 4; ++kc)
        accf = __builtin_amdgcn_mfma_f32_16x16x32_f16(af[kc], wfc[kc], accf, 0, 0, 0);
      if (lane < 32 && n16 < 7)
        lgring[t - 1][quad][n16] = accf[0];
    }

    if (t < T_) {
      #pragma unroll
      for (int ti = 0; ti < 8; ++ti) { acc[ti][0] = biasv[ti]; acc2[ti][0] = 0.0f; }
      // two 3-deep chain banks x 8 independent tiles
      #pragma unroll
      for (int kc = 0; kc < 3; ++kc) {
        #pragma unroll
        for (int ti = 0; ti < 8; ++ti)
          acc[ti] = __builtin_amdgcn_mfma_f32_16x16x32_f16(af[kc], wfrag[ti][kc], acc[ti], 0, 0, 0);
      }
      #pragma unroll
      for (int ti = 0; ti < 8; ++ti)
        acc2[ti] = __builtin_amdgcn_mfma_f32_16x16x32_f16(af[3], wfrag[ti][3], acc2[ti], 0, 0, 0);
      #pragma unroll
      for (int ti = 0; ti < 8; ++ti)
        acc2[ti] = __builtin_amdgcn_mfma_f32_16x16x32_f16(af4, wfrag[ti][4], acc2[ti], 0, 0, 0);

      // prefetch next x fragment (independent of everything below)
      if (aload && quad < 2 && t + 1 < T_)
        af4 = *(const half8*)&xlds[t + 1][arow][quad * 8];

      // cell update, lanes 0-31, both col-groups, no cross-lane exchange
      if (lane < 32) {
        float g0[4], g1[4];
        #pragma unroll
        for (int g = 0; g < 4; ++g) {
          g0[g] = acc[2 * g][0]     + acc2[2 * g][0];
          g1[g] = acc[2 * g + 1][0] + acc2[2 * g + 1][0];
        }
        const float iv0 = sigmoid_f(g0[0]);
        const float fv0 = sigmoid_f(g0[1]);
        const float gg0 = tanh_f(g0[2]);
        const float ov0 = sigmoid_f(g0[3]);
        c0 = fv0 * c0 + iv0 * gg0;
        const float hv0 = ov0 * tanh_f(c0);
        const float iv1 = sigmoid_f(g1[0]);
        const float fv1 = sigmoid_f(g1[1]);
        const float gg1 = tanh_f(g1[2]);
        const float ov1 = sigmoid_f(g1[3]);
        c1 = fv1 * c1 + iv1 * gg1;
        const float hv1 = ov1 * tanh_f(c1);
        abuf[(t + 1) & 1][hrow][32 * wave + n16]      = (_Float16)hv0;
        abuf[(t + 1) & 1][hrow][32 * wave + 16 + n16] = (_Float16)hv1;
      }
    }

    __syncthreads();
  }

  // ---- phase 2: softmax of all 2048 logit rows -> out ----
  for (int r = tid; r < T_ * 2; r += 256) {
    const int t = r >> 1;
    const int b = r & 1;
    float lg[7];
    float mx = -3.0e38f;
    #pragma unroll
    for (int k = 0; k < 7; ++k) {
      lg[k] = lgring[t][b][k];
      mx = fmaxf(mx, lg[k]);
    }
    float s = 0.0f;
    #pragma unroll
    for (int k = 0; k < 7; ++k) {
      lg[k] = fast_exp2(LOG2E * (lg[k] - mx));
      s += lg[k];
    }
    const float rs = fast_rcp(s);
    float* op = &out[((size_t)t * B_ + wgb + b) * 7];
    #pragma unroll
    for (int k = 0; k < 7; ++k) op[k] = lg[k] * rs;
  }
}

extern "C" void kernel_launch(void* const* d_in, const int* in_sizes, int n_in,
                              void* d_out, int out_size, void* d_ws, size_t ws_size,
                              hipStream_t stream) {
  (void)in_sizes; (void)n_in; (void)out_size; (void)d_ws; (void)ws_size;
  const float* x   = (const float*)d_in[0];
  const float* Wih = (const float*)d_in[1];
  const float* Whh = (const float*)d_in[2];
  const float* bih = (const float*)d_in[3];
  const float* bhh = (const float*)d_in[4];
  const float* Wfc = (const float*)d_in[5];
  const float* bfc = (const float*)d_in[6];
  hipLaunchKernelGGL(lstm_fused, dim3(256), dim3(256), 0, stream,
                     x, Wih, Whh, bih, bhh, Wfc, bfc, (float*)d_out);
}

// Round 5
// 829.833 us; speedup vs baseline: 1.3551x; 1.3551x over previous
//
#include <hip/hip_runtime.h>

#define H_ 128
#define T_ 1024
#define B_ 512
#define I_ 13
#define LOG2E 1.4426950408889634f

typedef _Float16 half8 __attribute__((ext_vector_type(8)));
typedef float float4_ __attribute__((ext_vector_type(4)));

static __device__ __forceinline__ float fast_rcp(float v) {
  return __builtin_amdgcn_rcpf(v);
}
static __device__ __forceinline__ float fast_exp2(float v) {
  return __builtin_amdgcn_exp2f(v);
}
static __device__ __forceinline__ float sigmoid_f(float v) {
  return fast_rcp(1.0f + fast_exp2(-LOG2E * v));
}
static __device__ __forceinline__ float tanh_f(float v) {
  return 2.0f * fast_rcp(1.0f + fast_exp2(-2.0f * LOG2E * v)) - 1.0f;
}

// R10 = R8 (932us, measured-best activation structure) + x-preaccumulation.
// R9 post-mortem: serializing two activation sets (no-shfl) + acc2 split
// LENGTHENED the serial tail (VALUBusy 34->47, dur +21%). Reverted.
// Change here: the x-gate contribution (kc=4) is h-independent, so it is
// pre-accumulated into acc at the END of step t for step t+1 (with the
// bias init riding along). The h-dependent ladder shrinks 5 -> 4 chunks,
// and af4-prefetch + acc-init leave the critical path. FC (wave 3) issues
// FIRST so its 4-deep chain drains under the gate ladder, not after it.
// Structure: 256 WGs x 4 waves, 2 rows/WG, 1 wave/SIMD, weights
// VGPR-resident, zero vector-memory ops in the loop.
__global__ __launch_bounds__(256, 1) void lstm_fused(
    const float* __restrict__ x, const float* __restrict__ Wih,
    const float* __restrict__ Whh, const float* __restrict__ bih,
    const float* __restrict__ bhh, const float* __restrict__ Wfc,
    const float* __restrict__ bfc, float* __restrict__ out)
{
  // 64 KB: x(t) for both rows (f16), slots 13..15 zero (pad to k-chunk)
  __shared__ __align__(16) _Float16 xlds[T_][2][16];
  // 64 KB: logits ring, slot t holds logits for output row t (cols 0..6)
  __shared__ __align__(16) float lgring[T_][2][8];
  // 1.3 KB: double-buffered h (cols 0..127 used; stride 168 halfs)
  __shared__ __align__(16) _Float16 abuf[2][2][168];

  const int tid  = threadIdx.x;
  const int wave = tid >> 6;      // 0..3
  const int lane = tid & 63;
  const int n16  = lane & 15;
  const int quad = lane >> 4;
  const int wgb  = blockIdx.x * 2;

  // ---- W fragments: wave w owns tiles {g*8 + 2w + p : g=0..3, p=0..1} ----
  // (all 4 gates for col-groups 2w and 2w+1 -> cell update is wave-local)
  // B layout (16x16x32): lane holds B[k = quad*8 + j][n = n16]
  half8 wfrag[8][5];
  float biasv[8];
  #pragma unroll
  for (int ti = 0; ti < 8; ++ti) {
    const int g    = ti >> 1;
    const int p    = ti & 1;
    const int tile = g * 8 + 2 * wave + p;
    const int col  = tile * 16 + n16;
    biasv[ti] = bih[col] + bhh[col];
    #pragma unroll
    for (int kc = 0; kc < 5; ++kc) {
      half8 f;
      #pragma unroll
      for (int j = 0; j < 8; ++j) {
        const int k = kc * 32 + quad * 8 + j;
        float v = 0.0f;
        if (k < 128)            v = Whh[col * H_ + k];
        else if (k < 128 + I_)  v = Wih[col * I_ + (k - 128)];
        f[j] = (_Float16)v;
      }
      wfrag[ti][kc] = f;
    }
  }
  // FC tile (consumed by wave 3; loaded uniformly), k < 128 -> 4 chunks
  half8 wfc[4];
  const float biasfc = (n16 < 7) ? bfc[n16] : 0.0f;
  #pragma unroll
  for (int kc = 0; kc < 4; ++kc) {
    half8 f;
    #pragma unroll
    for (int j = 0; j < 8; ++j) {
      const int k = kc * 32 + quad * 8 + j;
      f[j] = (_Float16)((n16 < 7) ? Wfc[n16 * H_ + k] : 0.0f);
    }
    wfc[kc] = f;
  }

  // ---- phase 0: preload all x for this WG into LDS (f16), zero pads ----
  for (int idx = tid; idx < T_ * 2 * 16; idx += 256) {
    const int t  = idx >> 5;
    const int rw = (idx >> 4) & 1;
    const int ii = idx & 15;
    float v = 0.0f;
    if (ii < I_) v = x[((size_t)t * B_ + wgb + rw) * I_ + ii];
    xlds[t][rw][ii] = (_Float16)v;
  }
  for (int idx = tid; idx < 2 * 2 * 168; idx += 256)
    ((_Float16*)abuf)[idx] = (_Float16)0.0f;
  __syncthreads();

  // cell state: full wave. lane -> (row=(lane>>4)&1, col=32w+(lane>=32?16:0)+n16)
  float c_state = 0.0f;
  const int  hrow = (lane >> 4) & 1;
  const int  hcol = 32 * wave + ((lane >= 32) ? 16 : 0) + n16;
  const bool aload = (n16 == 0) || (n16 == 4);  // A rows 0 and 4
  const int  arow  = n16 >> 2;

  half8 af[4];
  half8 af4;
  {
    half8 z;
    #pragma unroll
    for (int j = 0; j < 8; ++j) z[j] = (_Float16)0.0f;
    #pragma unroll
    for (int kc = 0; kc < 4; ++kc) af[kc] = z;
    af4 = z;
  }
  if (aload && quad < 2)
    af4 = *(const half8*)&xlds[0][arow][quad * 8];

  float4_ acc[8];
  #pragma unroll
  for (int ti = 0; ti < 8; ++ti)
    #pragma unroll
    for (int r = 0; r < 4; ++r) acc[ti][r] = 0.0f;
  float4_ accf;
  #pragma unroll
  for (int r = 0; r < 4; ++r) accf[r] = 0.0f;

  // prologue: acc = bias + xg(t=0)  (x-part pre-accumulated, off-path)
  #pragma unroll
  for (int ti = 0; ti < 8; ++ti) acc[ti][0] = biasv[ti];
  #pragma unroll
  for (int ti = 0; ti < 8; ++ti)
    acc[ti] = __builtin_amdgcn_mfma_f32_16x16x32_f16(af4, wfrag[ti][4], acc[ti], 0, 0, 0);

  // ---- phase 1: the recurrence. No vector-memory ops in this loop. ----
  for (int t = 0; t <= T_; ++t) {
    // A fragments: h chunks 0..3 from abuf
    if (aload) {
      #pragma unroll
      for (int kc = 0; kc < 4; ++kc)
        af[kc] = *(const half8*)&abuf[t & 1][arow][kc * 32 + quad * 8];
    }

    // FC logits FIRST (wave 3): depends only on af; its 4-deep chain
    // drains under the gate ladder instead of extending the barrier tail.
    if (wave == 3 && t >= 1) {
      accf[0] = biasfc;
      #pragma unroll
      for (int kc = 0; kc < 4; ++kc)
        accf = __builtin_amdgcn_mfma_f32_16x16x32_f16(af[kc], wfc[kc], accf, 0, 0, 0);
      if (lane < 32 && n16 < 7)
        lgring[t - 1][quad][n16] = accf[0];
    }

    if (t < T_) {
      // h-dependent ladder: 4 chunks (acc already holds bias + xg_t)
      #pragma unroll
      for (int kc = 0; kc < 4; ++kc) {
        #pragma unroll
        for (int ti = 0; ti < 8; ++ti)
          acc[ti] = __builtin_amdgcn_mfma_f32_16x16x32_f16(af[kc], wfrag[ti][kc], acc[ti], 0, 0, 0);
      }

      // issue next x-fragment load early (latency hides under activations)
      if (aload && quad < 2 && t + 1 < T_)
        af4 = *(const half8*)&xlds[t + 1][arow][quad * 8];

      // cell update, FULL wave (R8 structure, measured-best):
      // lanes<32 take pair p=0, lanes>=32 take pair p=1 via shuffle.
      float gv[4];
      #pragma unroll
      for (int g = 0; g < 4; ++g) {
        const float vB = __shfl(acc[2 * g + 1][0], lane & 31);
        gv[g] = (lane < 32) ? acc[2 * g][0] : vB;
      }
      const float iv = sigmoid_f(gv[0]);
      const float fv = sigmoid_f(gv[1]);
      const float gg = tanh_f(gv[2]);
      const float ov = sigmoid_f(gv[3]);
      c_state = fv * c_state + iv * gg;
      const float hv = ov * tanh_f(c_state);
      abuf[(t + 1) & 1][hrow][hcol] = (_Float16)hv;

      // re-init + x-preaccumulation for step t+1 (h-independent: fills
      // the stall between activations and the barrier)
      #pragma unroll
      for (int ti = 0; ti < 8; ++ti) acc[ti][0] = biasv[ti];
      #pragma unroll
      for (int ti = 0; ti < 8; ++ti)
        acc[ti] = __builtin_amdgcn_mfma_f32_16x16x32_f16(af4, wfrag[ti][4], acc[ti], 0, 0, 0);
    }

    __syncthreads();
  }

  // ---- phase 2: softmax of all 2048 logit rows -> out ----
  for (int r = tid; r < T_ * 2; r += 256) {
    const int t = r >> 1;
    const int b = r & 1;
    float lg[7];
    float mx = -3.0e38f;
    #pragma unroll
    for (int k = 0; k < 7; ++k) {
      lg[k] = lgring[t][b][k];
      mx = fmaxf(mx, lg[k]);
    }
    float s = 0.0f;
    #pragma unroll
    for (int k = 0; k < 7; ++k) {
      lg[k] = fast_exp2(LOG2E * (lg[k] - mx));
      s += lg[k];
    }
    const float rs = fast_rcp(s);
    float* op = &out[((size_t)t * B_ + wgb + b) * 7];
    #pragma unroll
    for (int k = 0; k < 7; ++k) op[k] = lg[k] * rs;
  }
}

extern "C" void kernel_launch(void* const* d_in, const int* in_sizes, int n_in,
                              void* d_out, int out_size, void* d_ws, size_t ws_size,
                              hipStream_t stream) {
  (void)in_sizes; (void)n_in; (void)out_size; (void)d_ws; (void)ws_size;
  const float* x   = (const float*)d_in[0];
  const float* Wih = (const float*)d_in[1];
  const float* Whh = (const float*)d_in[2];
  const float* bih = (const float*)d_in[3];
  const float* bhh = (const float*)d_in[4];
  const float* Wfc = (const float*)d_in[5];
  const float* bfc = (const float*)d_in[6];
  hipLaunchKernelGGL(lstm_fused, dim3(256), dim3(256), 0, stream,
                     x, Wih, Whh, bih, bhh, Wfc, bfc, (float*)d_out);
}